// Round 2
// baseline (279.388 us; speedup 1.0000x reference)
//
#include <hip/hip_runtime.h>

typedef __attribute__((ext_vector_type(8))) short bf16x8;
typedef __attribute__((ext_vector_type(4))) float f32x4;

#define E_DIM 100
#define L_SEQ 20
#define NV    30000
#define NVP   30080
#define MROWS 2000
#define MPAD  2048
#define KP    128

__device__ inline float sigmoidf_(float x){ return 1.f/(1.f+expf(-x)); }
__device__ inline unsigned short f2bf(float f){
  unsigned int u = __float_as_uint(f);
  return (unsigned short)((u + 0x7fffu + ((u>>16)&1u)) >> 16);
}

// ---------------- A1: gx[b][t][j] = x_t . W_ih[j] + b_ih[j] + b_hh[j] ----------------
__global__ __launch_bounds__(512,1) void gatesx_kernel(
    const int* __restrict__ seq, const float* __restrict__ item,
    const float* __restrict__ W_ih, const float* __restrict__ b_ih,
    const float* __restrict__ b_hh, float* __restrict__ gx){
  int b = blockIdx.x, j = threadIdx.x;
  __shared__ float4 xsa[L_SEQ][25];
  // load all 20 item rows (500 float4, coalesced)
  for (int idx=j; idx<500; idx+=512){
    int t = idx/25, k = idx-t*25;
    xsa[t][k] = *(const float4*)(item + (size_t)seq[b*L_SEQ+t]*E_DIM + k*4);
  }
  __syncthreads();
  if (j < 400){
    float bias = b_ih[j] + b_hh[j];
    float4 w[25];
    const float4* wr = (const float4*)(W_ih + (size_t)j*E_DIM);
#pragma unroll
    for (int k=0;k<25;k++) w[k]=wr[k];
    for (int t=0;t<L_SEQ;t++){
      float acc = bias;
#pragma unroll
      for (int k=0;k<25;k++){ float4 x=xsa[t][k]; float4 ww=w[k]; acc += ww.x*x.x+ww.y*x.y+ww.z*x.z+ww.w*x.w; }
      gx[(size_t)(b*L_SEQ+t)*400 + j] = acc;
    }
  }
}

// ---------------- A2: sequential recurrence, W_hh cached in regs ----------------
__global__ __launch_bounds__(512,1) void lstm_rec_kernel(
    const float* __restrict__ gx, const float* __restrict__ W_hh,
    float* __restrict__ hu){
  int b = blockIdx.x, j = threadIdx.x;
  __shared__ float4 hs4[25]; float* hs = (float*)hs4;
  __shared__ float gsh[400];
  float4 whh[25];
  if (j < 400){
    const float4* wr = (const float4*)(W_hh + (size_t)j*E_DIM);
#pragma unroll
    for (int k=0;k<25;k++) whh[k]=wr[k];
  }
  if (j < 100) hs[j] = 0.f;
  float c = 0.f;
  for (int t=0;t<L_SEQ;t++){
    __syncthreads();                      // hs(t-1) visible
    if (j < 400){
      float acc = gx[(size_t)(b*L_SEQ+t)*400 + j];
#pragma unroll
      for (int k=0;k<25;k++){ float4 h=hs4[k]; float4 w=whh[k]; acc += w.x*h.x+w.y*h.y+w.z*h.z+w.w*h.w; }
      gsh[j] = acc;
    }
    __syncthreads();                      // gates done, hs reads done
    if (j < 100){
      float ig=sigmoidf_(gsh[j]), fg=sigmoidf_(gsh[j+100]);
      float gg=tanhf(gsh[j+200]), og=sigmoidf_(gsh[j+300]);
      c = fg*c + ig*gg;
      float h = og*tanhf(c);
      hs[j] = h;
      hu[(size_t)(b*L_SEQ+t)*E_DIM + j] = h;
    }
  }
}

// ---------------- B: st2 (first-token LSTM step) + ls2 ----------------
__global__ void stageb_kernel(
    const int* __restrict__ ss2, const int* __restrict__ sn2,
    const float* __restrict__ item, const float* __restrict__ user,
    const float* __restrict__ W_ih, const float* __restrict__ b_ih, const float* __restrict__ b_hh,
    const float* __restrict__ W1, float* __restrict__ ls2){
  int n = blockIdx.x, j = threadIdx.x;
  __shared__ float4 xs4[25];  float* xs  = (float*)xs4;
  __shared__ float4 cat4[50]; float* cat = (float*)cat4;
  if (j < 100){
    xs[j]  = item[(size_t)ss2[n*L_SEQ]*E_DIM + j];
    cat[j] = user[(size_t)sn2[n]*E_DIM + j];
  }
  __syncthreads();
  if (j < 100){
    float ai=b_ih[j]+b_hh[j], ag=b_ih[200+j]+b_hh[200+j], ao=b_ih[300+j]+b_hh[300+j];
    const float4* wi=(const float4*)(W_ih + (size_t)j*E_DIM);
    const float4* wg=(const float4*)(W_ih + (size_t)(200+j)*E_DIM);
    const float4* wo=(const float4*)(W_ih + (size_t)(300+j)*E_DIM);
#pragma unroll
    for (int k=0;k<25;k++){
      float4 x=xs4[k];
      float4 a=wi[k]; ai += a.x*x.x+a.y*x.y+a.z*x.z+a.w*x.w;
      float4 g=wg[k]; ag += g.x*x.x+g.y*x.y+g.z*x.z+g.w*x.w;
      float4 o=wo[k]; ao += o.x*x.x+o.y*x.y+o.z*x.z+o.w*x.w;
    }
    float c0 = sigmoidf_(ai)*tanhf(ag);
    cat[100+j] = sigmoidf_(ao)*tanhf(c0);
  }
  __syncthreads();
  if (j < 100){
    float acc = 0.f;
    const float4* w1=(const float4*)(W1 + (size_t)j*200);
#pragma unroll
    for (int k=0;k<50;k++){ float4 cc=cat4[k]; float4 w=w1[k]; acc += w.x*cc.x+w.y*cc.y+w.z*cc.z+w.w*cc.w; }
    ls2[n*E_DIM + j] = fmaxf(acc, 0.f);
  }
}

// ---------------- C: GAT -> h0[b][e] ----------------
__global__ void gat_kernel(const float* __restrict__ hu, const float* __restrict__ ls2,
                           const float* __restrict__ Wg0, float* __restrict__ h0){
  int b = blockIdx.x, j = threadIdx.x; // 128 threads
  __shared__ float ns[6][100];
  __shared__ float wsc[6];
  __shared__ float ctx[100];
  if (j < 100) ns[5][j] = hu[(size_t)(b*L_SEQ)*E_DIM + j];
  for (int idx=j; idx<500; idx+=128){ int k=idx/100, e=idx-k*100; ns[k][e] = ls2[(b*5+k)*E_DIM + e]; }
  __syncthreads();
  if (j < 6){ float s=0.f; for (int e=0;e<100;e++) s += ns[5][e]*ns[j][e]; wsc[j]=s; }
  __syncthreads();
  if (j == 0){
    float m=wsc[0]; for (int k=1;k<6;k++) m=fmaxf(m,wsc[k]);
    float sum=0.f;
    for (int k=0;k<6;k++){ float e_=expf(wsc[k]-m); wsc[k]=e_; sum+=e_; }
    float inv=1.f/sum;
    for (int k=0;k<6;k++) wsc[k]*=inv;
  }
  __syncthreads();
  if (j < 100){ float cx=0.f; for (int k=0;k<6;k++) cx += wsc[k]*ns[k][j]; ctx[j]=cx; }
  __syncthreads();
  if (j < 100){
    float acc=0.f;
    for (int e=0;e<100;e++) acc += ctx[e]*Wg0[e*E_DIM + j];  // coalesced over j
    h0[b*E_DIM + j] = fmaxf(acc, 0.f);
  }
}

// ---------------- D: sr rows (m=b*20+l), f32 -> bf16, K padded to 128 ----------------
__global__ void sr_kernel(const float* __restrict__ hu, const float* __restrict__ h0,
                          const float* __restrict__ W2, unsigned short* __restrict__ srb){
  int m = blockIdx.x, j = threadIdx.x; // 128 threads
  if (m >= MROWS){ srb[(size_t)m*KP + j] = 0; return; }
  __shared__ float4 cat4[50]; float* cat=(float*)cat4;
  int b = m / L_SEQ;
  if (j < 100){ cat[j] = hu[(size_t)m*E_DIM + j]; cat[100+j] = h0[b*E_DIM + j]; }
  __syncthreads();
  float acc = 0.f;
  if (j < 100){
    const float4* w2=(const float4*)(W2 + (size_t)j*200);
#pragma unroll
    for (int k=0;k<50;k++){ float4 cc=cat4[k]; float4 w=w2[k]; acc += w.x*cc.x+w.y*cc.y+w.z*cc.z+w.w*cc.w; }
  }
  srb[(size_t)m*KP + j] = (j < 100) ? f2bf(acc) : (unsigned short)0;
}

// ---------------- P: item_emb f32 -> bf16, padded [30080][128] ----------------
__global__ void itemb_kernel(const float* __restrict__ item, unsigned short* __restrict__ ib){
  int t = blockIdx.x*256 + threadIdx.x;
  int v = t >> 6; int k = (t & 63) << 1;
  float a = 0.f, b2 = 0.f;
  if (v < NV && k < 100){ a = item[(size_t)v*E_DIM + k]; b2 = item[(size_t)v*E_DIM + k + 1]; }
  unsigned int pack = (unsigned int)f2bf(a) | ((unsigned int)f2bf(b2) << 16);
  *(unsigned int*)(ib + (size_t)v*KP + k) = pack;
}

// ---------------- E: logits = srb @ ib^T (bf16 MFMA, f32 acc), masked ----------------
__global__ __launch_bounds__(256) void gemm_kernel(
    const unsigned short* __restrict__ srb, const unsigned short* __restrict__ ib,
    const int* __restrict__ mask, float* __restrict__ out){
  __shared__ unsigned short As[128*KP];
  __shared__ unsigned short Bs[128*KP];
  int tile_n = blockIdx.x, tile_m = blockIdx.y;
  int tid = threadIdx.x;
  const float4* Ag = (const float4*)(srb + (size_t)tile_m*128*KP);
  const float4* Bg = (const float4*)(ib  + (size_t)tile_n*128*KP);
  float4* As4=(float4*)As; float4* Bs4=(float4*)Bs;
#pragma unroll
  for (int i=0;i<8;i++){
    int chunk = i*256 + tid;
    int row = chunk >> 4;
    int cb  = (chunk & 15) << 4;            // byte offset in row
    int sw  = cb ^ ((row & 7) << 4);        // XOR swizzle (G4: D=128 bf16 rows)
    int di  = row*16 + (sw >> 4);
    As4[di] = Ag[chunk];
    Bs4[di] = Bg[chunk];
  }
  __syncthreads();
  int wave = tid >> 6, lane = tid & 63;
  int wm = (wave >> 1) << 6, wn = (wave & 1) << 6;
  int lrow = lane & 15, lq = lane >> 4;
  f32x4 acc[4][4];
#pragma unroll
  for (int i=0;i<4;i++)
#pragma unroll
    for (int jj=0;jj<4;jj++) acc[i][jj] = (f32x4){0.f,0.f,0.f,0.f};
#pragma unroll
  for (int kk=0;kk<4;kk++){
    int koffb = (kk*32 + lq*8) * 2;         // byte offset along K
    bf16x8 a[4], bfr[4];
#pragma unroll
    for (int i=0;i<4;i++){
      int row = wm + i*16 + lrow;
      int boff = koffb ^ ((row & 7) << 4);
      a[i] = *(const bf16x8*)(As + row*KP + (boff >> 1));
    }
#pragma unroll
    for (int jj=0;jj<4;jj++){
      int row = wn + jj*16 + lrow;
      int boff = koffb ^ ((row & 7) << 4);
      bfr[jj] = *(const bf16x8*)(Bs + row*KP + (boff >> 1));
    }
#pragma unroll
    for (int i=0;i<4;i++)
#pragma unroll
      for (int jj=0;jj<4;jj++)
        acc[i][jj] = __builtin_amdgcn_mfma_f32_16x16x32_bf16(a[i], bfr[jj], acc[i][jj], 0, 0, 0);
  }
  // epilogue: C/D layout col=lane&15, row=(lane>>4)*4+reg  [m89]
  int v0 = tile_n*128 + wn;
  int m0 = tile_m*128 + wm;
#pragma unroll
  for (int i=0;i<4;i++){
    int mbase = m0 + i*16 + lq*4;
#pragma unroll
    for (int jj=0;jj<4;jj++){
      int v = v0 + jj*16 + lrow;
      if (v < NV){
#pragma unroll
        for (int r=0;r<4;r++){
          int m = mbase + r;
          if (m < MROWS)
            out[(size_t)m*NV + v] = acc[i][jj][r] * (float)mask[m];
        }
      }
    }
  }
}

extern "C" void kernel_launch(void* const* d_in, const int* in_sizes, int n_in,
                              void* d_out, int out_size, void* d_ws, size_t ws_size,
                              hipStream_t stream) {
  const int*   seq  = (const int*)d_in[0];
  const int*   sn2  = (const int*)d_in[2];
  const int*   ss2  = (const int*)d_in[4];
  const int*   mask = (const int*)d_in[5];
  const float* user = (const float*)d_in[6];
  const float* item = (const float*)d_in[7];
  const float* W_ih = (const float*)d_in[8];
  const float* W_hh = (const float*)d_in[9];
  const float* b_ih = (const float*)d_in[10];
  const float* b_hh = (const float*)d_in[11];
  const float* W1   = (const float*)d_in[12];
  const float* W2   = (const float*)d_in[13];
  const float* Wg0  = (const float*)d_in[14];
  float* out = (float*)d_out;
  char* ws = (char*)d_ws;

  float* hu  = (float*)(ws + 0);                      //   800,000 B
  float* h0  = (float*)(ws + 800000);                 //    40,000 B
  float* ls2 = (float*)(ws + 840000);                 //   200,000 B
  float* gx  = (float*)(ws + 1048576);                // 3,200,000 B
  unsigned short* srb = (unsigned short*)(ws + 4456448);  // 524,288 B
  unsigned short* ib  = (unsigned short*)(ws + 5242880);  // 7,700,480 B

  gatesx_kernel<<<dim3(100), dim3(512), 0, stream>>>(seq, item, W_ih, b_ih, b_hh, gx);
  lstm_rec_kernel<<<dim3(100), dim3(512), 0, stream>>>(gx, W_hh, hu);
  stageb_kernel<<<dim3(500), dim3(128), 0, stream>>>(ss2, sn2, item, user, W_ih, b_ih, b_hh, W1, ls2);
  itemb_kernel<<<dim3(7520), dim3(256), 0, stream>>>(item, ib);
  gat_kernel<<<dim3(100), dim3(128), 0, stream>>>(hu, ls2, Wg0, h0);
  sr_kernel<<<dim3(MPAD), dim3(128), 0, stream>>>(hu, h0, W2, srb);
  gemm_kernel<<<dim3(235, 16), dim3(256), 0, stream>>>(srb, ib, mask, out);
}

// Round 3
// 224.334 us; speedup vs baseline: 1.2454x; 1.2454x over previous
//
#include <hip/hip_runtime.h>

typedef __attribute__((ext_vector_type(8))) short bf16x8;
typedef __attribute__((ext_vector_type(4))) float f32x4;

#define E_DIM 100
#define L_SEQ 20
#define NV    30000
#define NVP   30080
#define MROWS 2000
#define MPAD  2048
#define KP    128

__device__ inline float sigmoidf_(float x){ return 1.f/(1.f+expf(-x)); }
__device__ inline unsigned short f2bf(float f){
  unsigned int u = __float_as_uint(f);
  return (unsigned short)((u + 0x7fffu + ((u>>16)&1u)) >> 16);
}

// ---------------- A1: gx[b][t][j] = x_t . W_ih[j] + b_ih[j] + b_hh[j] ----------------
__global__ __launch_bounds__(512,1) void gatesx_kernel(
    const int* __restrict__ seq, const float* __restrict__ item,
    const float* __restrict__ W_ih, const float* __restrict__ b_ih,
    const float* __restrict__ b_hh, float* __restrict__ gx){
  int b = blockIdx.x, j = threadIdx.x;
  __shared__ float4 xsa[L_SEQ][25];
  for (int idx=j; idx<500; idx+=512){
    int t = idx/25, k = idx-t*25;
    xsa[t][k] = *(const float4*)(item + (size_t)seq[b*L_SEQ+t]*E_DIM + k*4);
  }
  __syncthreads();
  if (j < 400){
    float bias = b_ih[j] + b_hh[j];
    float4 w[25];
    const float4* wr = (const float4*)(W_ih + (size_t)j*E_DIM);
#pragma unroll
    for (int k=0;k<25;k++) w[k]=wr[k];
    for (int t=0;t<L_SEQ;t++){
      float acc = bias;
#pragma unroll
      for (int k=0;k<25;k++){ float4 x=xsa[t][k]; float4 ww=w[k]; acc += ww.x*x.x+ww.y*x.y+ww.z*x.z+ww.w*x.w; }
      gx[(size_t)(b*L_SEQ+t)*400 + j] = acc;
    }
  }
}

// ---------------- A2: sequential recurrence, W_hh cached in regs ----------------
__global__ __launch_bounds__(512,1) void lstm_rec_kernel(
    const float* __restrict__ gx, const float* __restrict__ W_hh,
    float* __restrict__ hu){
  int b = blockIdx.x, j = threadIdx.x;
  __shared__ float4 hs4[25]; float* hs = (float*)hs4;
  __shared__ float gsh[400];
  float4 whh[25];
  if (j < 400){
    const float4* wr = (const float4*)(W_hh + (size_t)j*E_DIM);
#pragma unroll
    for (int k=0;k<25;k++) whh[k]=wr[k];
  }
  if (j < 100) hs[j] = 0.f;
  float c = 0.f;
  for (int t=0;t<L_SEQ;t++){
    __syncthreads();                      // hs(t-1) visible
    if (j < 400){
      float acc = gx[(size_t)(b*L_SEQ+t)*400 + j];
#pragma unroll
      for (int k=0;k<25;k++){ float4 h=hs4[k]; float4 w=whh[k]; acc += w.x*h.x+w.y*h.y+w.z*h.z+w.w*h.w; }
      gsh[j] = acc;
    }
    __syncthreads();                      // gates done, hs reads done
    if (j < 100){
      float ig=sigmoidf_(gsh[j]), fg=sigmoidf_(gsh[j+100]);
      float gg=tanhf(gsh[j+200]), og=sigmoidf_(gsh[j+300]);
      c = fg*c + ig*gg;
      float h = og*tanhf(c);
      hs[j] = h;
      hu[(size_t)(b*L_SEQ+t)*E_DIM + j] = h;
    }
  }
}

// ---------------- B: st2 (first-token LSTM step) + ls2 ----------------
__global__ void stageb_kernel(
    const int* __restrict__ ss2, const int* __restrict__ sn2,
    const float* __restrict__ item, const float* __restrict__ user,
    const float* __restrict__ W_ih, const float* __restrict__ b_ih, const float* __restrict__ b_hh,
    const float* __restrict__ W1, float* __restrict__ ls2){
  int n = blockIdx.x, j = threadIdx.x;
  __shared__ float4 xs4[25];  float* xs  = (float*)xs4;
  __shared__ float4 cat4[50]; float* cat = (float*)cat4;
  if (j < 100){
    xs[j]  = item[(size_t)ss2[n*L_SEQ]*E_DIM + j];
    cat[j] = user[(size_t)sn2[n]*E_DIM + j];
  }
  __syncthreads();
  if (j < 100){
    float ai=b_ih[j]+b_hh[j], ag=b_ih[200+j]+b_hh[200+j], ao=b_ih[300+j]+b_hh[300+j];
    const float4* wi=(const float4*)(W_ih + (size_t)j*E_DIM);
    const float4* wg=(const float4*)(W_ih + (size_t)(200+j)*E_DIM);
    const float4* wo=(const float4*)(W_ih + (size_t)(300+j)*E_DIM);
#pragma unroll
    for (int k=0;k<25;k++){
      float4 x=xs4[k];
      float4 a=wi[k]; ai += a.x*x.x+a.y*x.y+a.z*x.z+a.w*x.w;
      float4 g=wg[k]; ag += g.x*x.x+g.y*x.y+g.z*x.z+g.w*x.w;
      float4 o=wo[k]; ao += o.x*x.x+o.y*x.y+o.z*x.z+o.w*x.w;
    }
    float c0 = sigmoidf_(ai)*tanhf(ag);
    cat[100+j] = sigmoidf_(ao)*tanhf(c0);
  }
  __syncthreads();
  if (j < 100){
    float acc = 0.f;
    const float4* w1=(const float4*)(W1 + (size_t)j*200);
#pragma unroll
    for (int k=0;k<50;k++){ float4 cc=cat4[k]; float4 w=w1[k]; acc += w.x*cc.x+w.y*cc.y+w.z*cc.z+w.w*cc.w; }
    ls2[n*E_DIM + j] = fmaxf(acc, 0.f);
  }
}

// ---------------- C: GAT -> h0[b][e] ----------------
__global__ void gat_kernel(const float* __restrict__ hu, const float* __restrict__ ls2,
                           const float* __restrict__ Wg0, float* __restrict__ h0){
  int b = blockIdx.x, j = threadIdx.x; // 128 threads
  __shared__ float ns[6][100];
  __shared__ float wsc[6];
  __shared__ float ctx[100];
  if (j < 100) ns[5][j] = hu[(size_t)(b*L_SEQ)*E_DIM + j];
  for (int idx=j; idx<500; idx+=128){ int k=idx/100, e=idx-k*100; ns[k][e] = ls2[(b*5+k)*E_DIM + e]; }
  __syncthreads();
  if (j < 6){ float s=0.f; for (int e=0;e<100;e++) s += ns[5][e]*ns[j][e]; wsc[j]=s; }
  __syncthreads();
  if (j == 0){
    float m=wsc[0]; for (int k=1;k<6;k++) m=fmaxf(m,wsc[k]);
    float sum=0.f;
    for (int k=0;k<6;k++){ float e_=expf(wsc[k]-m); wsc[k]=e_; sum+=e_; }
    float inv=1.f/sum;
    for (int k=0;k<6;k++) wsc[k]*=inv;
  }
  __syncthreads();
  if (j < 100){ float cx=0.f; for (int k=0;k<6;k++) cx += wsc[k]*ns[k][j]; ctx[j]=cx; }
  __syncthreads();
  if (j < 100){
    float acc=0.f;
    for (int e=0;e<100;e++) acc += ctx[e]*Wg0[e*E_DIM + j];  // coalesced over j
    h0[b*E_DIM + j] = fmaxf(acc, 0.f);
  }
}

// ---------------- D: sr rows, mask folded in, f32 -> bf16, K padded to 128 ----------------
__global__ void sr_kernel(const float* __restrict__ hu, const float* __restrict__ h0,
                          const float* __restrict__ W2, const int* __restrict__ mask,
                          unsigned short* __restrict__ srb){
  int m = blockIdx.x, j = threadIdx.x; // 128 threads
  if (m >= MROWS){ srb[(size_t)m*KP + j] = 0; return; }
  __shared__ float4 cat4[50]; float* cat=(float*)cat4;
  int b = m / L_SEQ;
  if (j < 100){ cat[j] = hu[(size_t)m*E_DIM + j]; cat[100+j] = h0[b*E_DIM + j]; }
  __syncthreads();
  float acc = 0.f;
  if (j < 100){
    const float4* w2=(const float4*)(W2 + (size_t)j*200);
#pragma unroll
    for (int k=0;k<50;k++){ float4 cc=cat4[k]; float4 w=w2[k]; acc += w.x*cc.x+w.y*cc.y+w.z*cc.z+w.w*cc.w; }
    acc *= (float)mask[m];  // linearity: (sr*m) @ ib^T == m * (sr @ ib^T)
  }
  srb[(size_t)m*KP + j] = (j < 100) ? f2bf(acc) : (unsigned short)0;
}

// ---------------- P: item_emb f32 -> bf16, padded [30080][128] ----------------
__global__ void itemb_kernel(const float* __restrict__ item, unsigned short* __restrict__ ib){
  int t = blockIdx.x*256 + threadIdx.x;
  int v = t >> 6; int k = (t & 63) << 1;
  float a = 0.f, b2 = 0.f;
  if (v < NV && k < 100){ a = item[(size_t)v*E_DIM + k]; b2 = item[(size_t)v*E_DIM + k + 1]; }
  unsigned int pack = (unsigned int)f2bf(a) | ((unsigned int)f2bf(b2) << 16);
  *(unsigned int*)(ib + (size_t)v*KP + k) = pack;
}

// ---------------- E: logits = srb @ ib^T (bf16 MFMA, f32 acc) ----------------
// Swapped operands: A-op = ib rows (v on C/D-row axis), B-op = srb rows (m on
// C/D-col axis) -> acc f32x4 is 4 consecutive v -> dwordx4 stores, 16 full
// 64B lines per store instruction. XCD-bijective tile-column-major swizzle:
// each XCD owns a ~30-wide tile_n strip (~0.96MB of ib, L2-resident, 16x reuse).
__global__ __launch_bounds__(256) void gemm_kernel(
    const unsigned short* __restrict__ srb, const unsigned short* __restrict__ ib,
    float* __restrict__ out){
  __shared__ unsigned short As[128*KP];
  __shared__ unsigned short Bs[128*KP];
  // 3760 blocks = 8 XCDs * 470; tile-column-major (tile_n outer, tile_m inner)
  int orig = blockIdx.x;
  int wgid = (orig & 7)*470 + (orig >> 3);
  int tile_n = wgid >> 4;          // 0..234
  int tile_m = wgid & 15;          // 0..15
  int tid = threadIdx.x;
  const float4* Ag = (const float4*)(srb + (size_t)tile_m*128*KP);
  const float4* Bg = (const float4*)(ib  + (size_t)tile_n*128*KP);
  float4* As4=(float4*)As; float4* Bs4=(float4*)Bs;
#pragma unroll
  for (int i=0;i<8;i++){
    int chunk = i*256 + tid;
    int row = chunk >> 4;
    int cb  = (chunk & 15) << 4;            // byte offset in row
    int sw  = cb ^ ((row & 7) << 4);        // XOR swizzle (G4: D=128 bf16 rows)
    int di  = row*16 + (sw >> 4);
    As4[di] = Ag[chunk];
    Bs4[di] = Bg[chunk];
  }
  __syncthreads();
  int wave = tid >> 6, lane = tid & 63;
  int wm = (wave >> 1) << 6, wn = (wave & 1) << 6;   // wm: srb(m) offset, wn: ib(v) offset
  int lrow = lane & 15, lq = lane >> 4;
  f32x4 acc[4][4];
#pragma unroll
  for (int i=0;i<4;i++)
#pragma unroll
    for (int jj=0;jj<4;jj++) acc[i][jj] = (f32x4){0.f,0.f,0.f,0.f};
#pragma unroll
  for (int kk=0;kk<4;kk++){
    int koffb = (kk*32 + lq*8) * 2;         // byte offset along K
    bf16x8 a[4], bfr[4];
#pragma unroll
    for (int i=0;i<4;i++){
      int row = wm + i*16 + lrow;
      int boff = koffb ^ ((row & 7) << 4);
      a[i] = *(const bf16x8*)(As + row*KP + (boff >> 1));
    }
#pragma unroll
    for (int jj=0;jj<4;jj++){
      int row = wn + jj*16 + lrow;
      int boff = koffb ^ ((row & 7) << 4);
      bfr[jj] = *(const bf16x8*)(Bs + row*KP + (boff >> 1));
    }
#pragma unroll
    for (int i=0;i<4;i++)
#pragma unroll
      for (int jj=0;jj<4;jj++)
        acc[i][jj] = __builtin_amdgcn_mfma_f32_16x16x32_bf16(bfr[jj], a[i], acc[i][jj], 0, 0, 0);
  }
  // epilogue: C/D col(lane&15) = B-op row = m ; C/D row((lane>>4)*4+r) = A-op row = v
  int v0 = tile_n*128 + wn + lq*4;
  int m0 = tile_m*128 + wm + lrow;
#pragma unroll
  for (int i=0;i<4;i++){
    int m = m0 + i*16;
    if (m < MROWS){
#pragma unroll
      for (int jj=0;jj<4;jj++){
        int v = v0 + jj*16;
        if (v < NV)
          *(float4*)(out + (size_t)m*NV + v) = (float4){acc[i][jj][0], acc[i][jj][1], acc[i][jj][2], acc[i][jj][3]};
      }
    }
  }
}

extern "C" void kernel_launch(void* const* d_in, const int* in_sizes, int n_in,
                              void* d_out, int out_size, void* d_ws, size_t ws_size,
                              hipStream_t stream) {
  const int*   seq  = (const int*)d_in[0];
  const int*   sn2  = (const int*)d_in[2];
  const int*   ss2  = (const int*)d_in[4];
  const int*   mask = (const int*)d_in[5];
  const float* user = (const float*)d_in[6];
  const float* item = (const float*)d_in[7];
  const float* W_ih = (const float*)d_in[8];
  const float* W_hh = (const float*)d_in[9];
  const float* b_ih = (const float*)d_in[10];
  const float* b_hh = (const float*)d_in[11];
  const float* W1   = (const float*)d_in[12];
  const float* W2   = (const float*)d_in[13];
  const float* Wg0  = (const float*)d_in[14];
  float* out = (float*)d_out;
  char* ws = (char*)d_ws;

  float* hu  = (float*)(ws + 0);                      //   800,000 B
  float* h0  = (float*)(ws + 800000);                 //    40,000 B
  float* ls2 = (float*)(ws + 840000);                 //   200,000 B
  float* gx  = (float*)(ws + 1048576);                // 3,200,000 B
  unsigned short* srb = (unsigned short*)(ws + 4456448);  // 524,288 B
  unsigned short* ib  = (unsigned short*)(ws + 5242880);  // 7,700,480 B

  gatesx_kernel<<<dim3(100), dim3(512), 0, stream>>>(seq, item, W_ih, b_ih, b_hh, gx);
  lstm_rec_kernel<<<dim3(100), dim3(512), 0, stream>>>(gx, W_hh, hu);
  stageb_kernel<<<dim3(500), dim3(128), 0, stream>>>(ss2, sn2, item, user, W_ih, b_ih, b_hh, W1, ls2);
  itemb_kernel<<<dim3(7520), dim3(256), 0, stream>>>(item, ib);
  gat_kernel<<<dim3(100), dim3(128), 0, stream>>>(hu, ls2, Wg0, h0);
  sr_kernel<<<dim3(MPAD), dim3(128), 0, stream>>>(hu, h0, W2, mask, srb);
  gemm_kernel<<<dim3(3760), dim3(256), 0, stream>>>(srb, ib, out);
}

// Round 4
// 182.565 us; speedup vs baseline: 1.5303x; 1.2288x over previous
//
#include <hip/hip_runtime.h>

typedef __attribute__((ext_vector_type(8))) short bf16x8;
typedef __attribute__((ext_vector_type(4))) float f32x4;

#define E_DIM 100
#define L_SEQ 20
#define NV    30000
#define NVP   30080
#define MROWS 2000
#define MPAD  2048
#define KP    128

__device__ inline float sigmoidf_(float x){ return 1.f/(1.f+expf(-x)); }
__device__ inline unsigned short f2bf(float f){
  unsigned int u = __float_as_uint(f);
  return (unsigned short)((u + 0x7fffu + ((u>>16)&1u)) >> 16);
}

// ================= PREP: one block per session b =================
// Phases (all intra-block deps): fused LSTM -> stageb(5 sessions) -> GAT ->
// sr rows -> itemb slice. hu/ls2/h0 live only in LDS.
__global__ __launch_bounds__(512,1) void prep_kernel(
    const int* __restrict__ seq, const int* __restrict__ ss2,
    const int* __restrict__ sn2, const int* __restrict__ mask,
    const float* __restrict__ user, const float* __restrict__ item,
    const float* __restrict__ W_ih, const float* __restrict__ W_hh,
    const float* __restrict__ b_ih, const float* __restrict__ b_hh,
    const float* __restrict__ W1, const float* __restrict__ W2,
    const float* __restrict__ Wg0,
    unsigned short* __restrict__ srb, unsigned short* __restrict__ ib){
  int b = blockIdx.x, t = threadIdx.x;
  __shared__ float4 xs4[25];        float* xs  = (float*)xs4;
  __shared__ float4 hs4[25];        float* hs  = (float*)hs4;
  __shared__ float  gsh[400];
  __shared__ float4 hu4[L_SEQ][25];
  __shared__ float4 stxs4[5][25];   float* stxs = (float*)stxs4;
  __shared__ float4 stcat4[5][50];  float* stcat = (float*)stcat4;
  __shared__ float  ls2l[5][100];
  __shared__ float  ns[6][100];
  __shared__ float  wsc[8];
  __shared__ float  ctx[100];
  __shared__ float4 h04[25];        float* h0l = (float*)h04;

  // ---- phase 1: fused LSTM over session b ----
  float4 wih[25], whh[25];
  float bias = 0.f;
  if (t < 400){
    const float4* wi = (const float4*)(W_ih + (size_t)t*E_DIM);
    const float4* wh = (const float4*)(W_hh + (size_t)t*E_DIM);
#pragma unroll
    for (int k=0;k<25;k++) wih[k]=wi[k];
#pragma unroll
    for (int k=0;k<25;k++) whh[k]=wh[k];
    bias = b_ih[t] + b_hh[t];
  }
  if (t < 100) hs[t] = 0.f;
  float c = 0.f;
  for (int tt=0; tt<L_SEQ; tt++){
    if (t < 100) xs[t] = item[(size_t)seq[b*L_SEQ+tt]*E_DIM + t];
    __syncthreads();                    // xs(t) ready, hs(t-1) visible
    if (t < 400){
      float acc = bias;
#pragma unroll
      for (int k=0;k<25;k++){ float4 x=xs4[k]; float4 w=wih[k]; acc += w.x*x.x+w.y*x.y+w.z*x.z+w.w*x.w; }
#pragma unroll
      for (int k=0;k<25;k++){ float4 h=hs4[k]; float4 w=whh[k]; acc += w.x*h.x+w.y*h.y+w.z*h.z+w.w*h.w; }
      gsh[t] = acc;
    }
    __syncthreads();                    // gates done, hs reads done
    if (t < 100){
      float ig=sigmoidf_(gsh[t]), fg=sigmoidf_(gsh[t+100]);
      float gg=tanhf(gsh[t+200]), og=sigmoidf_(gsh[t+300]);
      c = fg*c + ig*gg;
      float h = og*tanhf(c);
      hs[t] = h;
      ((float*)hu4[tt])[t] = h;
    }
  }

  // ---- phase 2: stageb for sessions n = 5b..5b+4 ----
  int s = t / 100, j = t - s*100;       // t<500 active
  if (t < 500){
    int n = b*5 + s;
    stxs[s*100 + j]  = item[(size_t)ss2[n*L_SEQ]*E_DIM + j];
    stcat[s*200 + j] = user[(size_t)sn2[n]*E_DIM + j];
  }
  __syncthreads();
  if (t < 500){
    float ai=b_ih[j]+b_hh[j], ag=b_ih[200+j]+b_hh[200+j], ao=b_ih[300+j]+b_hh[300+j];
    const float4* wi=(const float4*)(W_ih + (size_t)j*E_DIM);
    const float4* wg=(const float4*)(W_ih + (size_t)(200+j)*E_DIM);
    const float4* wo=(const float4*)(W_ih + (size_t)(300+j)*E_DIM);
#pragma unroll
    for (int k=0;k<25;k++){
      float4 x=stxs4[s][k];
      float4 a=wi[k]; ai += a.x*x.x+a.y*x.y+a.z*x.z+a.w*x.w;
      float4 g=wg[k]; ag += g.x*x.x+g.y*x.y+g.z*x.z+g.w*x.w;
      float4 o=wo[k]; ao += o.x*x.x+o.y*x.y+o.z*x.z+o.w*x.w;
    }
    float c0 = sigmoidf_(ai)*tanhf(ag);
    stcat[s*200 + 100 + j] = sigmoidf_(ao)*tanhf(c0);
  }
  __syncthreads();
  if (t < 500){
    float acc = 0.f;
    const float4* w1=(const float4*)(W1 + (size_t)j*200);
#pragma unroll
    for (int k=0;k<50;k++){ float4 cc=stcat4[s][k]; float4 w=w1[k]; acc += w.x*cc.x+w.y*cc.y+w.z*cc.z+w.w*cc.w; }
    ls2l[s][j] = fmaxf(acc, 0.f);
  }
  __syncthreads();

  // ---- phase 3: GAT -> h0l ----
  if (t < 100) ns[5][t] = ((float*)hu4[0])[t];
  if (t < 500) ns[s][j] = ls2l[s][j];
  __syncthreads();
  if (t < 6){ float sc=0.f; for (int e=0;e<100;e++) sc += ns[5][e]*ns[t][e]; wsc[t]=sc; }
  __syncthreads();
  if (t == 0){
    float m=wsc[0]; for (int k=1;k<6;k++) m=fmaxf(m,wsc[k]);
    float sum=0.f;
    for (int k=0;k<6;k++){ float e_=expf(wsc[k]-m); wsc[k]=e_; sum+=e_; }
    float inv=1.f/sum;
    for (int k=0;k<6;k++) wsc[k]*=inv;
  }
  __syncthreads();
  if (t < 100){ float cx=0.f; for (int k=0;k<6;k++) cx += wsc[k]*ns[k][t]; ctx[t]=cx; }
  __syncthreads();
  if (t < 100){
    float acc=0.f;
    for (int e=0;e<100;e++) acc += ctx[e]*Wg0[e*E_DIM + t];
    h0l[t] = fmaxf(acc, 0.f);
  }
  __syncthreads();

  // ---- phase 4: sr rows m = 20b..20b+19 (mask folded), bf16, K-pad ----
  {
    int mi4 = t >> 7;                   // 0..3
    int jj  = t & 127;                  // 0..127
#pragma unroll
    for (int r=0;r<5;r++){
      int mi = r*4 + mi4;
      int m  = b*L_SEQ + mi;
      unsigned short val = 0;
      if (jj < 100){
        float acc = 0.f;
        const float4* w2=(const float4*)(W2 + (size_t)jj*200);
#pragma unroll
        for (int k=0;k<25;k++){ float4 cc=hu4[mi][k]; float4 w=w2[k];    acc += w.x*cc.x+w.y*cc.y+w.z*cc.z+w.w*cc.w; }
#pragma unroll
        for (int k=0;k<25;k++){ float4 cc=h04[k];     float4 w=w2[25+k]; acc += w.x*cc.x+w.y*cc.y+w.z*cc.z+w.w*cc.w; }
        acc *= (float)mask[m];
        val = f2bf(acc);
      }
      srb[(size_t)m*KP + jj] = val;
    }
    // pad rows 2000..2047 -> zero (blocks 0..47)
    if (b < 48 && t < 128) srb[(size_t)(MROWS + b)*KP + t] = 0;
  }

  // ---- phase 5: itemb slice: rows [b*301, b*301+301) ----
  {
    int v0 = b*301;
    int cnt = (v0 + 301 <= NVP) ? 301 : (NVP - v0);
    for (int idx = t; idx < cnt*64; idx += 512){
      int v  = v0 + (idx >> 6);
      int k2 = (idx & 63) << 1;
      float a = 0.f, bb = 0.f;
      if (v < NV && k2 < 100){ a = item[(size_t)v*E_DIM + k2]; bb = item[(size_t)v*E_DIM + k2 + 1]; }
      unsigned int pack = (unsigned int)f2bf(a) | ((unsigned int)f2bf(bb) << 16);
      *(unsigned int*)(ib + (size_t)v*KP + k2) = pack;
    }
  }
}

// ================= GEMM: logits = srb @ ib^T (bf16 MFMA, f32 acc) ========
// Operand-swapped (A-op = ib rows -> v on C/D row axis) => float4 stores.
// Swizzle: each XCD owns 2 m-panels, sweeps tile_n contiguously (tile_m is
// the fastest bit) -> concurrent writes form ~16KB runs per row; ib tile
// shared by the adjacent tile_m pair (L2 hit).
__global__ __launch_bounds__(256) void gemm_kernel(
    const unsigned short* __restrict__ srb, const unsigned short* __restrict__ ib,
    float* __restrict__ out){
  __shared__ unsigned short As[128*KP];
  __shared__ unsigned short Bs[128*KP];
  int orig = blockIdx.x;               // 0..3759 = 8 XCD * 470
  int xcd  = orig & 7;
  int p    = orig >> 3;                // sequential within an XCD
  int tile_n = p >> 1;                 // 0..234
  int tile_m = (xcd << 1) | (p & 1);   // 0..15
  int tid = threadIdx.x;
  const float4* Ag = (const float4*)(srb + (size_t)tile_m*128*KP);
  const float4* Bg = (const float4*)(ib  + (size_t)tile_n*128*KP);
  float4* As4=(float4*)As; float4* Bs4=(float4*)Bs;
#pragma unroll
  for (int i=0;i<8;i++){
    int chunk = i*256 + tid;
    int row = chunk >> 4;
    int cb  = (chunk & 15) << 4;
    int sw  = cb ^ ((row & 7) << 4);   // XOR swizzle (G4: D=128 bf16 rows)
    int di  = row*16 + (sw >> 4);
    As4[di] = Ag[chunk];
    Bs4[di] = Bg[chunk];
  }
  __syncthreads();
  int wave = tid >> 6, lane = tid & 63;
  int wm = (wave >> 1) << 6, wn = (wave & 1) << 6;
  int lrow = lane & 15, lq = lane >> 4;
  f32x4 acc[4][4];
#pragma unroll
  for (int i=0;i<4;i++)
#pragma unroll
    for (int jj=0;jj<4;jj++) acc[i][jj] = (f32x4){0.f,0.f,0.f,0.f};
#pragma unroll
  for (int kk=0;kk<4;kk++){
    int koffb = (kk*32 + lq*8) * 2;
    bf16x8 a[4], bfr[4];
#pragma unroll
    for (int i=0;i<4;i++){
      int row = wm + i*16 + lrow;
      int boff = koffb ^ ((row & 7) << 4);
      a[i] = *(const bf16x8*)(As + row*KP + (boff >> 1));
    }
#pragma unroll
    for (int jj=0;jj<4;jj++){
      int row = wn + jj*16 + lrow;
      int boff = koffb ^ ((row & 7) << 4);
      bfr[jj] = *(const bf16x8*)(Bs + row*KP + (boff >> 1));
    }
#pragma unroll
    for (int i=0;i<4;i++)
#pragma unroll
      for (int jj=0;jj<4;jj++)
        acc[i][jj] = __builtin_amdgcn_mfma_f32_16x16x32_bf16(bfr[jj], a[i], acc[i][jj], 0, 0, 0);
  }
  // C/D col(lane&15) = srb row (m); C/D row((lane>>4)*4+r) = ib row (v)
  int v0 = tile_n*128 + wn + lq*4;
  int m0 = tile_m*128 + wm + lrow;
#pragma unroll
  for (int i=0;i<4;i++){
    int m = m0 + i*16;
    if (m < MROWS){
#pragma unroll
      for (int jj=0;jj<4;jj++){
        int v = v0 + jj*16;
        if (v < NV)
          *(float4*)(out + (size_t)m*NV + v) = (float4){acc[i][jj][0], acc[i][jj][1], acc[i][jj][2], acc[i][jj][3]};
      }
    }
  }
}

extern "C" void kernel_launch(void* const* d_in, const int* in_sizes, int n_in,
                              void* d_out, int out_size, void* d_ws, size_t ws_size,
                              hipStream_t stream) {
  const int*   seq  = (const int*)d_in[0];
  const int*   sn2  = (const int*)d_in[2];
  const int*   ss2  = (const int*)d_in[4];
  const int*   mask = (const int*)d_in[5];
  const float* user = (const float*)d_in[6];
  const float* item = (const float*)d_in[7];
  const float* W_ih = (const float*)d_in[8];
  const float* W_hh = (const float*)d_in[9];
  const float* b_ih = (const float*)d_in[10];
  const float* b_hh = (const float*)d_in[11];
  const float* W1   = (const float*)d_in[12];
  const float* W2   = (const float*)d_in[13];
  const float* Wg0  = (const float*)d_in[14];
  float* out = (float*)d_out;
  char* ws = (char*)d_ws;

  unsigned short* srb = (unsigned short*)(ws);            // 2048*128*2 = 524,288 B
  unsigned short* ib  = (unsigned short*)(ws + 1048576);  // 30080*128*2 = 7,700,480 B

  prep_kernel<<<dim3(100), dim3(512), 0, stream>>>(
      seq, ss2, sn2, mask, user, item, W_ih, W_hh, b_ih, b_hh, W1, W2, Wg0, srb, ib);
  gemm_kernel<<<dim3(3760), dim3(256), 0, stream>>>(srb, ib, out);
}

// Round 5
// 180.001 us; speedup vs baseline: 1.5521x; 1.0142x over previous
//
#include <hip/hip_runtime.h>

typedef __attribute__((ext_vector_type(8))) short bf16x8;
typedef __attribute__((ext_vector_type(4))) float f32x4;

#define E_DIM 100
#define L_SEQ 20
#define NV    30000
#define NVP   30080
#define MROWS 2000
#define MPAD  2048
#define KP    128

__device__ inline float sigmoidf_(float x){ return 1.f/(1.f+expf(-x)); }
__device__ inline unsigned short f2bf(float f){
  unsigned int u = __float_as_uint(f);
  return (unsigned short)((u + 0x7fffu + ((u>>16)&1u)) >> 16);
}

// ================= PREP: one block per session b =================
// Phase 1a: gxl[t][j] = x_t . W_ih[j] + bias   (only wih[25] live: 100 VGPR)
// Phase 1b: recurrence with whh[25] live only  (disjoint lifetime -> no spill;
//           R4's fused version held 200 VGPRs against a 128 cap and spilled)
// Then: stageb(5) -> GAT -> sr rows -> itemb slice. All intra-block deps.
__global__ __launch_bounds__(512,1) void prep_kernel(
    const int* __restrict__ seq, const int* __restrict__ ss2,
    const int* __restrict__ sn2, const int* __restrict__ mask,
    const float* __restrict__ user, const float* __restrict__ item,
    const float* __restrict__ W_ih, const float* __restrict__ W_hh,
    const float* __restrict__ b_ih, const float* __restrict__ b_hh,
    const float* __restrict__ W1, const float* __restrict__ W2,
    const float* __restrict__ Wg0,
    unsigned short* __restrict__ srb, unsigned short* __restrict__ ib){
  int b = blockIdx.x, t = threadIdx.x;
  __shared__ float4 xsa[L_SEQ][25];
  __shared__ float  gxl[L_SEQ][400];
  __shared__ float4 hs4[25];        float* hs  = (float*)hs4;
  __shared__ float  gsh[400];
  __shared__ float4 hu4[L_SEQ][25];
  __shared__ float4 stxs4[5][25];   float* stxs = (float*)stxs4;
  __shared__ float4 stcat4[5][50];  float* stcat = (float*)stcat4;
  __shared__ float  ls2l[5][100];
  __shared__ float  ns[6][100];
  __shared__ float  wsc[8];
  __shared__ float  ctx[100];
  __shared__ float4 h04[25];        float* h0l = (float*)h04;

  // ---- phase 1a: stage all 20 x rows, compute x-part of gates ----
  for (int idx=t; idx<500; idx+=512){
    int tt = idx/25, k = idx-tt*25;
    xsa[tt][k] = *(const float4*)(item + (size_t)seq[b*L_SEQ+tt]*E_DIM + k*4);
  }
  float bias = 0.f;
  if (t < 400) bias = b_ih[t] + b_hh[t];
  __syncthreads();
  if (t < 400){
    float4 w[25];
    const float4* wr = (const float4*)(W_ih + (size_t)t*E_DIM);
#pragma unroll
    for (int k=0;k<25;k++) w[k]=wr[k];
    for (int tt=0; tt<L_SEQ; tt++){
      float acc = bias;
#pragma unroll
      for (int k=0;k<25;k++){ float4 x=xsa[tt][k]; float4 ww=w[k]; acc += ww.x*x.x+ww.y*x.y+ww.z*x.z+ww.w*x.w; }
      gxl[tt][t] = acc;
    }
  }
  __builtin_amdgcn_sched_barrier(0);   // keep whh loads out of phase 1a (VGPR peak)

  // ---- phase 1b: recurrence (only whh live) ----
  float4 whh[25];
  if (t < 400){
    const float4* wr = (const float4*)(W_hh + (size_t)t*E_DIM);
#pragma unroll
    for (int k=0;k<25;k++) whh[k]=wr[k];
  }
  if (t < 100) hs[t] = 0.f;
  float c = 0.f;
  __syncthreads();                     // hs init + gxl visible
  for (int tt=0; tt<L_SEQ; tt++){
    if (t < 400){
      float acc = gxl[tt][t];
#pragma unroll
      for (int k=0;k<25;k++){ float4 h=hs4[k]; float4 w=whh[k]; acc += w.x*h.x+w.y*h.y+w.z*h.z+w.w*h.w; }
      gsh[t] = acc;
    }
    __syncthreads();                   // gates done, hs reads done
    if (t < 100){
      float ig=sigmoidf_(gsh[t]), fg=sigmoidf_(gsh[t+100]);
      float gg=tanhf(gsh[t+200]), og=sigmoidf_(gsh[t+300]);
      c = fg*c + ig*gg;
      float h = og*tanhf(c);
      hs[t] = h;
      ((float*)hu4[tt])[t] = h;
    }
    __syncthreads();                   // hs(t) visible for next step
  }

  // ---- phase 2: stageb for sessions n = 5b..5b+4 ----
  int s = t / 100, j = t - s*100;       // t<500 active
  if (t < 500){
    int n = b*5 + s;
    stxs[s*100 + j]  = item[(size_t)ss2[n*L_SEQ]*E_DIM + j];
    stcat[s*200 + j] = user[(size_t)sn2[n]*E_DIM + j];
  }
  __syncthreads();
  if (t < 500){
    float ai=b_ih[j]+b_hh[j], ag=b_ih[200+j]+b_hh[200+j], ao=b_ih[300+j]+b_hh[300+j];
    const float4* wi=(const float4*)(W_ih + (size_t)j*E_DIM);
    const float4* wg=(const float4*)(W_ih + (size_t)(200+j)*E_DIM);
    const float4* wo=(const float4*)(W_ih + (size_t)(300+j)*E_DIM);
#pragma unroll
    for (int k=0;k<25;k++){
      float4 x=stxs4[s][k];
      float4 a=wi[k]; ai += a.x*x.x+a.y*x.y+a.z*x.z+a.w*x.w;
      float4 g=wg[k]; ag += g.x*x.x+g.y*x.y+g.z*x.z+g.w*x.w;
      float4 o=wo[k]; ao += o.x*x.x+o.y*x.y+o.z*x.z+o.w*x.w;
    }
    float c0 = sigmoidf_(ai)*tanhf(ag);
    stcat[s*200 + 100 + j] = sigmoidf_(ao)*tanhf(c0);
  }
  __syncthreads();
  if (t < 500){
    float acc = 0.f;
    const float4* w1=(const float4*)(W1 + (size_t)j*200);
#pragma unroll
    for (int k=0;k<50;k++){ float4 cc=stcat4[s][k]; float4 w=w1[k]; acc += w.x*cc.x+w.y*cc.y+w.z*cc.z+w.w*cc.w; }
    ls2l[s][j] = fmaxf(acc, 0.f);
  }
  __syncthreads();

  // ---- phase 3: GAT -> h0l ----
  if (t < 100) ns[5][t] = ((float*)hu4[0])[t];
  if (t < 500) ns[s][j] = ls2l[s][j];
  __syncthreads();
  if (t < 6){ float sc=0.f; for (int e=0;e<100;e++) sc += ns[5][e]*ns[t][e]; wsc[t]=sc; }
  __syncthreads();
  if (t == 0){
    float m=wsc[0]; for (int k=1;k<6;k++) m=fmaxf(m,wsc[k]);
    float sum=0.f;
    for (int k=0;k<6;k++){ float e_=expf(wsc[k]-m); wsc[k]=e_; sum+=e_; }
    float inv=1.f/sum;
    for (int k=0;k<6;k++) wsc[k]*=inv;
  }
  __syncthreads();
  if (t < 100){ float cx=0.f; for (int k=0;k<6;k++) cx += wsc[k]*ns[k][t]; ctx[t]=cx; }
  __syncthreads();
  if (t < 100){
    float acc=0.f;
    for (int e=0;e<100;e++) acc += ctx[e]*Wg0[e*E_DIM + t];
    h0l[t] = fmaxf(acc, 0.f);
  }
  __syncthreads();

  // ---- phase 4: sr rows m = 20b..20b+19 (mask folded), bf16, K-pad ----
  {
    int mi4 = t >> 7;                   // 0..3
    int jj  = t & 127;                  // 0..127
#pragma unroll
    for (int r=0;r<5;r++){
      int mi = r*4 + mi4;
      int m  = b*L_SEQ + mi;
      unsigned short val = 0;
      if (jj < 100){
        float acc = 0.f;
        const float4* w2=(const float4*)(W2 + (size_t)jj*200);
#pragma unroll
        for (int k=0;k<25;k++){ float4 cc=hu4[mi][k]; float4 w=w2[k];    acc += w.x*cc.x+w.y*cc.y+w.z*cc.z+w.w*cc.w; }
#pragma unroll
        for (int k=0;k<25;k++){ float4 cc=h04[k];     float4 w=w2[25+k]; acc += w.x*cc.x+w.y*cc.y+w.z*cc.z+w.w*cc.w; }
        acc *= (float)mask[m];
        val = f2bf(acc);
      }
      srb[(size_t)m*KP + jj] = val;
    }
    // pad rows 2000..2047 -> zero (blocks 0..47)
    if (b < 48 && t < 128) srb[(size_t)(MROWS + b)*KP + t] = 0;
  }

  // ---- phase 5: itemb slice: rows [b*301, b*301+301) ----
  {
    int v0 = b*301;
    int cnt = (v0 + 301 <= NVP) ? 301 : (NVP - v0);
    for (int idx = t; idx < cnt*64; idx += 512){
      int v  = v0 + (idx >> 6);
      int k2 = (idx & 63) << 1;
      float a = 0.f, bb = 0.f;
      if (v < NV && k2 < 100){ a = item[(size_t)v*E_DIM + k2]; bb = item[(size_t)v*E_DIM + k2 + 1]; }
      unsigned int pack = (unsigned int)f2bf(a) | ((unsigned int)f2bf(bb) << 16);
      *(unsigned int*)(ib + (size_t)v*KP + k2) = pack;
    }
  }
}

// ================= GEMM: logits = srb @ ib^T (bf16 MFMA, f32 acc) ========
// Operand-swapped (A-op = ib rows -> v on C/D row axis) => float4 stores.
// Swizzle: each XCD owns 2 m-panels, sweeps tile_n contiguously.
__global__ __launch_bounds__(256) void gemm_kernel(
    const unsigned short* __restrict__ srb, const unsigned short* __restrict__ ib,
    float* __restrict__ out){
  __shared__ unsigned short As[128*KP];
  __shared__ unsigned short Bs[128*KP];
  int orig = blockIdx.x;               // 0..3759 = 8 XCD * 470
  int xcd  = orig & 7;
  int p    = orig >> 3;                // sequential within an XCD
  int tile_n = p >> 1;                 // 0..234
  int tile_m = (xcd << 1) | (p & 1);   // 0..15
  int tid = threadIdx.x;
  const float4* Ag = (const float4*)(srb + (size_t)tile_m*128*KP);
  const float4* Bg = (const float4*)(ib  + (size_t)tile_n*128*KP);
  float4* As4=(float4*)As; float4* Bs4=(float4*)Bs;
#pragma unroll
  for (int i=0;i<8;i++){
    int chunk = i*256 + tid;
    int row = chunk >> 4;
    int cb  = (chunk & 15) << 4;
    int sw  = cb ^ ((row & 7) << 4);   // XOR swizzle (G4: D=128 bf16 rows)
    int di  = row*16 + (sw >> 4);
    As4[di] = Ag[chunk];
    Bs4[di] = Bg[chunk];
  }
  __syncthreads();
  int wave = tid >> 6, lane = tid & 63;
  int wm = (wave >> 1) << 6, wn = (wave & 1) << 6;
  int lrow = lane & 15, lq = lane >> 4;
  f32x4 acc[4][4];
#pragma unroll
  for (int i=0;i<4;i++)
#pragma unroll
    for (int jj=0;jj<4;jj++) acc[i][jj] = (f32x4){0.f,0.f,0.f,0.f};
#pragma unroll
  for (int kk=0;kk<4;kk++){
    int koffb = (kk*32 + lq*8) * 2;
    bf16x8 a[4], bfr[4];
#pragma unroll
    for (int i=0;i<4;i++){
      int row = wm + i*16 + lrow;
      int boff = koffb ^ ((row & 7) << 4);
      a[i] = *(const bf16x8*)(As + row*KP + (boff >> 1));
    }
#pragma unroll
    for (int jj=0;jj<4;jj++){
      int row = wn + jj*16 + lrow;
      int boff = koffb ^ ((row & 7) << 4);
      bfr[jj] = *(const bf16x8*)(Bs + row*KP + (boff >> 1));
    }
#pragma unroll
    for (int i=0;i<4;i++)
#pragma unroll
      for (int jj=0;jj<4;jj++)
        acc[i][jj] = __builtin_amdgcn_mfma_f32_16x16x32_bf16(bfr[jj], a[i], acc[i][jj], 0, 0, 0);
  }
  // C/D col(lane&15) = srb row (m); C/D row((lane>>4)*4+r) = ib row (v)
  int v0 = tile_n*128 + wn + lq*4;
  int m0 = tile_m*128 + wm + lrow;
#pragma unroll
  for (int i=0;i<4;i++){
    int m = m0 + i*16;
    if (m < MROWS){
#pragma unroll
      for (int jj=0;jj<4;jj++){
        int v = v0 + jj*16;
        if (v < NV)
          *(float4*)(out + (size_t)m*NV + v) = (float4){acc[i][jj][0], acc[i][jj][1], acc[i][jj][2], acc[i][jj][3]};
      }
    }
  }
}

extern "C" void kernel_launch(void* const* d_in, const int* in_sizes, int n_in,
                              void* d_out, int out_size, void* d_ws, size_t ws_size,
                              hipStream_t stream) {
  const int*   seq  = (const int*)d_in[0];
  const int*   sn2  = (const int*)d_in[2];
  const int*   ss2  = (const int*)d_in[4];
  const int*   mask = (const int*)d_in[5];
  const float* user = (const float*)d_in[6];
  const float* item = (const float*)d_in[7];
  const float* W_ih = (const float*)d_in[8];
  const float* W_hh = (const float*)d_in[9];
  const float* b_ih = (const float*)d_in[10];
  const float* b_hh = (const float*)d_in[11];
  const float* W1   = (const float*)d_in[12];
  const float* W2   = (const float*)d_in[13];
  const float* Wg0  = (const float*)d_in[14];
  float* out = (float*)d_out;
  char* ws = (char*)d_ws;

  unsigned short* srb = (unsigned short*)(ws);            // 2048*128*2 = 524,288 B
  unsigned short* ib  = (unsigned short*)(ws + 1048576);  // 30080*128*2 = 7,700,480 B

  prep_kernel<<<dim3(100), dim3(512), 0, stream>>>(
      seq, ss2, sn2, mask, user, item, W_ih, W_hh, b_ih, b_hh, W1, W2, Wg0, srb, ib);
  gemm_kernel<<<dim3(3760), dim3(256), 0, stream>>>(srb, ib, out);
}